// Round 1
// baseline (659.656 us; speedup 1.0000x reference)
//
#include <hip/hip_runtime.h>
#include <math.h>

#define C 64
#define D 16
#define EPSF 1e-8f
#define DVAR 0.5f
#define DDIST 1.5f

__device__ __forceinline__ void lds_addf(float* p, float v) {
    __hip_atomic_fetch_add(p, v, __ATOMIC_RELAXED, __HIP_MEMORY_SCOPE_WORKGROUP);
}
__device__ __forceinline__ void glb_addf(float* p, float v) {
    __hip_atomic_fetch_add(p, v, __ATOMIC_RELAXED, __HIP_MEMORY_SCOPE_AGENT);
}

// ws layout (floats): [0,1024) sums, [1024,1088) counts (uint), [1088,1152) hinge sums
__global__ __launch_bounds__(256) void k_zero(float* ws, int n) {
    int i = blockIdx.x * 256 + threadIdx.x;
    if (i < n) ws[i] = 0.0f;
}

__global__ __launch_bounds__(256) void k_sums(const float4* __restrict__ f4,
                                              const int* __restrict__ labels, int N,
                                              float* __restrict__ g_sums,
                                              unsigned* __restrict__ g_cnt) {
    // stride-17 padding: unpadded (16c+d)%32 hits only 2 banks per d-step
    __shared__ float s_sums[C * 17];
    __shared__ unsigned s_cnt[C];
    int t = threadIdx.x;
    for (int i = t; i < C * 17; i += 256) s_sums[i] = 0.0f;
    if (t < C) s_cnt[t] = 0u;
    __syncthreads();

    int gid = blockIdx.x * 256 + t;
    int stride = gridDim.x * 256;
    for (int p = gid; p < N; p += stride) {
        int c = labels[p];
        float4 a = f4[4 * p + 0];
        float4 b = f4[4 * p + 1];
        float4 cc = f4[4 * p + 2];
        float4 dd = f4[4 * p + 3];
        float* row = &s_sums[c * 17];
        lds_addf(row + 0, a.x);  lds_addf(row + 1, a.y);
        lds_addf(row + 2, a.z);  lds_addf(row + 3, a.w);
        lds_addf(row + 4, b.x);  lds_addf(row + 5, b.y);
        lds_addf(row + 6, b.z);  lds_addf(row + 7, b.w);
        lds_addf(row + 8, cc.x); lds_addf(row + 9, cc.y);
        lds_addf(row + 10, cc.z); lds_addf(row + 11, cc.w);
        lds_addf(row + 12, dd.x); lds_addf(row + 13, dd.y);
        lds_addf(row + 14, dd.z); lds_addf(row + 15, dd.w);
        atomicAdd(&s_cnt[c], 1u);
    }
    __syncthreads();
    for (int i = t; i < C * D; i += 256) {
        int c = i >> 4, d = i & 15;
        glb_addf(&g_sums[i], s_sums[c * 17 + d]);
    }
    if (t < C) atomicAdd(&g_cnt[t], s_cnt[t]);
}

__global__ __launch_bounds__(256) void k_hinge(const float4* __restrict__ f4,
                                               const int* __restrict__ labels, int N,
                                               const float* __restrict__ g_sums,
                                               const unsigned* __restrict__ g_cnt,
                                               float* __restrict__ g_h) {
    // stride 20: float4-aligned (80 B rows) and bank-spread
    __shared__ float s_means[C * 20];
    __shared__ float s_h[C];
    int t = threadIdx.x;
    for (int i = t; i < C * D; i += 256) {
        int c = i >> 4, d = i & 15;
        float cnt = fmaxf((float)g_cnt[c], 1.0f);
        s_means[c * 20 + d] = g_sums[i] / cnt;
    }
    if (t < C) s_h[t] = 0.0f;
    __syncthreads();

    int gid = blockIdx.x * 256 + t;
    int stride = gridDim.x * 256;
    for (int p = gid; p < N; p += stride) {
        int c = labels[p];
        const float4* m4 = reinterpret_cast<const float4*>(&s_means[c * 20]);
        float4 m0 = m4[0], m1 = m4[1], m2 = m4[2], m3 = m4[3];
        float4 a = f4[4 * p + 0];
        float4 b = f4[4 * p + 1];
        float4 cc = f4[4 * p + 2];
        float4 dd = f4[4 * p + 3];
        float ss = 0.0f, dx;
        dx = a.x - m0.x + EPSF; ss += dx * dx;
        dx = a.y - m0.y + EPSF; ss += dx * dx;
        dx = a.z - m0.z + EPSF; ss += dx * dx;
        dx = a.w - m0.w + EPSF; ss += dx * dx;
        dx = b.x - m1.x + EPSF; ss += dx * dx;
        dx = b.y - m1.y + EPSF; ss += dx * dx;
        dx = b.z - m1.z + EPSF; ss += dx * dx;
        dx = b.w - m1.w + EPSF; ss += dx * dx;
        dx = cc.x - m2.x + EPSF; ss += dx * dx;
        dx = cc.y - m2.y + EPSF; ss += dx * dx;
        dx = cc.z - m2.z + EPSF; ss += dx * dx;
        dx = cc.w - m2.w + EPSF; ss += dx * dx;
        dx = dd.x - m3.x + EPSF; ss += dx * dx;
        dx = dd.y - m3.y + EPSF; ss += dx * dx;
        dx = dd.z - m3.z + EPSF; ss += dx * dx;
        dx = dd.w - m3.w + EPSF; ss += dx * dx;
        float dist = sqrtf(ss);
        float h = fmaxf(dist - DVAR, 0.0f);
        lds_addf(&s_h[c], h * h);
    }
    __syncthreads();
    if (t < C) glb_addf(&g_h[t], s_h[t]);
}

__global__ __launch_bounds__(256) void k_final(const float* __restrict__ g_sums,
                                               const unsigned* __restrict__ g_cnt,
                                               const float* __restrict__ g_h,
                                               float* __restrict__ out) {
    __shared__ float s_m[C * 17];
    __shared__ float red[256];
    int t = threadIdx.x;
    for (int i = t; i < C * D; i += 256) {
        int c = i >> 4, d = i & 15;
        s_m[c * 17 + d] = g_sums[i] / fmaxf((float)g_cnt[c], 1.0f);
    }
    __syncthreads();

    // var_loss = mean_c( hinge_sum_c / count_c )
    float v = 0.0f;
    if (t < C) v = g_h[t] / fmaxf((float)g_cnt[t], 1.0f);
    red[t] = v;
    __syncthreads();
    for (int s = 128; s > 0; s >>= 1) {
        if (t < s) red[t] += red[t + s];
        __syncthreads();
    }
    float var_loss = red[0] / (float)C;
    __syncthreads();

    // dist_loss over ordered pairs i != j
    float ds = 0.0f;
    for (int p = t; p < C * C; p += 256) {
        int i = p >> 6, j = p & 63;
        if (i != j) {
            float ss = 0.0f;
            #pragma unroll
            for (int d = 0; d < D; d++) {
                float df = s_m[i * 17 + d] - s_m[j * 17 + d] + EPSF;
                ss += df * df;
            }
            float pd = sqrtf(ss);
            float h = fmaxf(2.0f * DDIST - pd, 0.0f);
            ds += h * h;
        }
    }
    red[t] = ds;
    __syncthreads();
    for (int s = 128; s > 0; s >>= 1) {
        if (t < s) red[t] += red[t + s];
        __syncthreads();
    }
    float dist_loss = red[0] / (float)(C * (C - 1));
    __syncthreads();

    // reg_loss = mean_c ||m_c + EPS||
    float rg = 0.0f;
    if (t < C) {
        float ss = 0.0f;
        #pragma unroll
        for (int d = 0; d < D; d++) {
            float m = s_m[t * 17 + d] + EPSF;
            ss += m * m;
        }
        rg = sqrtf(ss);
    }
    red[t] = rg;
    __syncthreads();
    for (int s = 128; s > 0; s >>= 1) {
        if (t < s) red[t] += red[t + s];
        __syncthreads();
    }
    float reg_loss = red[0] / (float)C;

    if (t == 0) {
        out[0] = var_loss + dist_loss + 0.001f * reg_loss;
        out[1] = var_loss;
        out[2] = dist_loss;
        out[3] = reg_loss;
    }
}

extern "C" void kernel_launch(void* const* d_in, const int* in_sizes, int n_in,
                              void* d_out, int out_size, void* d_ws, size_t ws_size,
                              hipStream_t stream) {
    const float* features = (const float*)d_in[0];
    const int* labels = (const int*)d_in[1];
    int N = in_sizes[0] / D;

    float* ws = (float*)d_ws;
    float* g_sums = ws;                          // 1024 floats
    unsigned* g_cnt = (unsigned*)(ws + 1024);    // 64 uints
    float* g_h = ws + 1088;                      // 64 floats
    float* out = (float*)d_out;

    hipLaunchKernelGGL(k_zero, dim3(5), dim3(256), 0, stream, ws, 1152);
    hipLaunchKernelGGL(k_sums, dim3(2048), dim3(256), 0, stream,
                       (const float4*)features, labels, N, g_sums, g_cnt);
    hipLaunchKernelGGL(k_hinge, dim3(2048), dim3(256), 0, stream,
                       (const float4*)features, labels, N, g_sums, g_cnt, g_h);
    hipLaunchKernelGGL(k_final, dim3(1), dim3(256), 0, stream, g_sums, g_cnt, g_h, out);
}

// Round 6
// 415.913 us; speedup vs baseline: 1.5860x; 1.5860x over previous
//
#include <hip/hip_runtime.h>
#include <math.h>

#define C 64
#define D 16
#define EPSF 1e-8f
#define DVAR 0.5f
#define DDIST 1.5f
#define FPSCALE 65536.0f
#define INV_FPSCALE (1.0f / 65536.0f)

// ws layout (floats): [0,1024) g_sums, [1024,1088) g_cnt(uint), [1088] g_var
__global__ __launch_bounds__(256) void k_zero(float* ws, int n) {
    int i = blockIdx.x * 256 + threadIdx.x;
    if (i < n) ws[i] = 0.0f;
}

__global__ __launch_bounds__(256) void k_sums(const float4* __restrict__ f4,
                                              const int* __restrict__ labels, int N,
                                              float* __restrict__ g_sums,
                                              unsigned* __restrict__ g_cnt) {
    // round-1-proven structure; fp32 LDS CAS atomics replaced by native int ds_add.
    // stride-17 rows: (c*17+d)%32 spreads random c over all banks (~2-way, free per m136)
    __shared__ int s_sums[C * 17];
    __shared__ unsigned s_cnt[C];
    int t = threadIdx.x;
    for (int i = t; i < C * 17; i += 256) s_sums[i] = 0;
    if (t < C) s_cnt[t] = 0u;
    __syncthreads();

    int gid = blockIdx.x * 256 + t;
    int stride = gridDim.x * 256;
    for (int p = gid; p < N; p += stride) {
        int c = labels[p] & (C - 1);
        float4 a  = f4[4 * p + 0];
        float4 b  = f4[4 * p + 1];
        float4 cc = f4[4 * p + 2];
        float4 dd = f4[4 * p + 3];
        int* row = &s_sums[c * 17];
        atomicAdd(row + 0,  __float2int_rn(a.x  * FPSCALE));
        atomicAdd(row + 1,  __float2int_rn(a.y  * FPSCALE));
        atomicAdd(row + 2,  __float2int_rn(a.z  * FPSCALE));
        atomicAdd(row + 3,  __float2int_rn(a.w  * FPSCALE));
        atomicAdd(row + 4,  __float2int_rn(b.x  * FPSCALE));
        atomicAdd(row + 5,  __float2int_rn(b.y  * FPSCALE));
        atomicAdd(row + 6,  __float2int_rn(b.z  * FPSCALE));
        atomicAdd(row + 7,  __float2int_rn(b.w  * FPSCALE));
        atomicAdd(row + 8,  __float2int_rn(cc.x * FPSCALE));
        atomicAdd(row + 9,  __float2int_rn(cc.y * FPSCALE));
        atomicAdd(row + 10, __float2int_rn(cc.z * FPSCALE));
        atomicAdd(row + 11, __float2int_rn(cc.w * FPSCALE));
        atomicAdd(row + 12, __float2int_rn(dd.x * FPSCALE));
        atomicAdd(row + 13, __float2int_rn(dd.y * FPSCALE));
        atomicAdd(row + 14, __float2int_rn(dd.z * FPSCALE));
        atomicAdd(row + 15, __float2int_rn(dd.w * FPSCALE));
        atomicAdd(&s_cnt[c], 1u);
    }
    __syncthreads();
    for (int i = t; i < C * D; i += 256) {
        int c = i >> 4, d = i & 15;
        atomicAdd(&g_sums[i], (float)s_sums[c * 17 + d] * INV_FPSCALE);
    }
    if (t < C) atomicAdd(&g_cnt[t], s_cnt[t]);
}

__global__ __launch_bounds__(256) void k_hinge(const float4* __restrict__ f4,
                                               const int* __restrict__ labels, int N,
                                               const float* __restrict__ g_sums,
                                               const unsigned* __restrict__ g_cnt,
                                               float* __restrict__ g_var) {
    // round-1-proven structure; per-point LDS fp atomic replaced by register
    // weighted sum: var_loss = sum_p h_p^2 / (C * count[label_p])
    __shared__ float s_means[C * 20];   // 20: float4-aligned rows, bank-spread
    __shared__ float s_w[C];
    __shared__ float s_red[256];
    int t = threadIdx.x;
    for (int i = t; i < C * D; i += 256) {
        int c = i >> 4, d = i & 15;
        s_means[c * 20 + d] = g_sums[i] / fmaxf((float)g_cnt[c], 1.0f);
    }
    if (t < C) s_w[t] = 1.0f / (fmaxf((float)g_cnt[t], 1.0f) * (float)C);
    __syncthreads();

    float acc = 0.0f;
    int gid = blockIdx.x * 256 + t;
    int stride = gridDim.x * 256;
    for (int p = gid; p < N; p += stride) {
        int c = labels[p] & (C - 1);
        const float* m = &s_means[c * 20];
        float4 m0 = *(const float4*)(m + 0);
        float4 m1 = *(const float4*)(m + 4);
        float4 m2 = *(const float4*)(m + 8);
        float4 m3 = *(const float4*)(m + 12);
        float4 a  = f4[4 * p + 0];
        float4 b  = f4[4 * p + 1];
        float4 cc = f4[4 * p + 2];
        float4 dd = f4[4 * p + 3];
        float ss = 0.0f, dx;
        dx = a.x - m0.x + EPSF; ss += dx * dx;
        dx = a.y - m0.y + EPSF; ss += dx * dx;
        dx = a.z - m0.z + EPSF; ss += dx * dx;
        dx = a.w - m0.w + EPSF; ss += dx * dx;
        dx = b.x - m1.x + EPSF; ss += dx * dx;
        dx = b.y - m1.y + EPSF; ss += dx * dx;
        dx = b.z - m1.z + EPSF; ss += dx * dx;
        dx = b.w - m1.w + EPSF; ss += dx * dx;
        dx = cc.x - m2.x + EPSF; ss += dx * dx;
        dx = cc.y - m2.y + EPSF; ss += dx * dx;
        dx = cc.z - m2.z + EPSF; ss += dx * dx;
        dx = cc.w - m2.w + EPSF; ss += dx * dx;
        dx = dd.x - m3.x + EPSF; ss += dx * dx;
        dx = dd.y - m3.y + EPSF; ss += dx * dx;
        dx = dd.z - m3.z + EPSF; ss += dx * dx;
        dx = dd.w - m3.w + EPSF; ss += dx * dx;
        float h = fmaxf(sqrtf(ss) - DVAR, 0.0f);
        acc += h * h * s_w[c];
    }
    s_red[t] = acc;
    __syncthreads();
    for (int s = 128; s > 0; s >>= 1) {
        if (t < s) s_red[t] += s_red[t + s];
        __syncthreads();
    }
    if (t == 0) atomicAdd(g_var, s_red[0]);
}

__global__ __launch_bounds__(256) void k_final(const float* __restrict__ g_sums,
                                               const unsigned* __restrict__ g_cnt,
                                               const float* __restrict__ g_var,
                                               float* __restrict__ out) {
    __shared__ float s_m[C * 17];
    __shared__ float red[256];
    int t = threadIdx.x;
    for (int i = t; i < C * D; i += 256) {
        int c = i >> 4, d = i & 15;
        s_m[c * 17 + d] = g_sums[i] / fmaxf((float)g_cnt[c], 1.0f);
    }
    __syncthreads();

    float var_loss = g_var[0];

    // dist_loss over ordered pairs i != j
    float ds = 0.0f;
    for (int p = t; p < C * C; p += 256) {
        int i = p >> 6, j = p & 63;
        if (i != j) {
            float ss = 0.0f;
            #pragma unroll
            for (int d = 0; d < D; d++) {
                float df = s_m[i * 17 + d] - s_m[j * 17 + d] + EPSF;
                ss += df * df;
            }
            float h = fmaxf(2.0f * DDIST - sqrtf(ss), 0.0f);
            ds += h * h;
        }
    }
    red[t] = ds;
    __syncthreads();
    for (int s = 128; s > 0; s >>= 1) {
        if (t < s) red[t] += red[t + s];
        __syncthreads();
    }
    float dist_loss = red[0] / (float)(C * (C - 1));
    __syncthreads();

    // reg_loss = mean_c ||m_c + EPS||
    float rg = 0.0f;
    if (t < C) {
        float ss = 0.0f;
        #pragma unroll
        for (int d = 0; d < D; d++) {
            float m = s_m[t * 17 + d] + EPSF;
            ss += m * m;
        }
        rg = sqrtf(ss);
    }
    red[t] = rg;
    __syncthreads();
    for (int s = 128; s > 0; s >>= 1) {
        if (t < s) red[t] += red[t + s];
        __syncthreads();
    }
    float reg_loss = red[0] / (float)C;

    if (t == 0) {
        out[0] = var_loss + dist_loss + 0.001f * reg_loss;
        out[1] = var_loss;
        out[2] = dist_loss;
        out[3] = reg_loss;
    }
}

extern "C" void kernel_launch(void* const* d_in, const int* in_sizes, int n_in,
                              void* d_out, int out_size, void* d_ws, size_t ws_size,
                              hipStream_t stream) {
    const float* features = (const float*)d_in[0];
    const int* labels = (const int*)d_in[1];
    int N = in_sizes[0] / D;

    float* ws = (float*)d_ws;
    float* g_sums = ws;                          // 1024 floats
    unsigned* g_cnt = (unsigned*)(ws + 1024);    // 64 uints
    float* g_var = ws + 1088;                    // 1 float
    float* out = (float*)d_out;

    hipLaunchKernelGGL(k_zero, dim3(5), dim3(256), 0, stream, ws, 1152);
    hipLaunchKernelGGL(k_sums, dim3(2048), dim3(256), 0, stream,
                       (const float4*)features, labels, N, g_sums, g_cnt);
    hipLaunchKernelGGL(k_hinge, dim3(2048), dim3(256), 0, stream,
                       (const float4*)features, labels, N, g_sums, g_cnt, g_var);
    hipLaunchKernelGGL(k_final, dim3(1), dim3(256), 0, stream, g_sums, g_cnt, g_var, out);
}

// Round 7
// 415.811 us; speedup vs baseline: 1.5864x; 1.0002x over previous
//
#include <hip/hip_runtime.h>
#include <math.h>

#define C 64
#define D 16
#define EPSF 1e-8f
#define DVAR 0.5f
#define DDIST 1.5f
#define FPSCALE 65536.0f
#define INV_FPSCALE (1.0f / 65536.0f)
#define NREP 4
#define REPSTRIDE 1089   // 64*17 + 1: copy k shifted k banks; bank=(copy+17c+d)%32 uniform

// ws layout (floats): [0,1024) g_sums, [1024,1088) g_cnt(uint), [1088] g_var
__global__ __launch_bounds__(256) void k_zero(float* ws, int n) {
    int i = blockIdx.x * 256 + threadIdx.x;
    if (i < n) ws[i] = 0.0f;
}

__global__ __launch_bounds__(256) void k_sums(const float4* __restrict__ f4,
                                              const int* __restrict__ labels, int N,
                                              float* __restrict__ g_sums,
                                              unsigned* __restrict__ g_cnt) {
    // 4-replica fixed-point histogram: replica = t&3 cuts same-address RMW
    // serialization from ~4-way (64 lanes over 64 clusters) to ~2-way
    // (16 lanes per replica over 64 clusters). Bank spread stays uniform.
    __shared__ int s_sums[NREP * REPSTRIDE];   // 17.4 KB
    __shared__ unsigned s_cnt[C];
    int t = threadIdx.x;
    for (int i = t; i < NREP * REPSTRIDE; i += 256) s_sums[i] = 0;
    if (t < C) s_cnt[t] = 0u;
    __syncthreads();

    int* myrep = &s_sums[(t & 3) * REPSTRIDE];
    int gid = blockIdx.x * 256 + t;
    int stride = gridDim.x * 256;
    for (int p = gid; p < N; p += stride) {
        int c = labels[p] & (C - 1);
        float4 a  = f4[4 * p + 0];
        float4 b  = f4[4 * p + 1];
        float4 cc = f4[4 * p + 2];
        float4 dd = f4[4 * p + 3];
        int* row = myrep + c * 17;
        atomicAdd(row + 0,  __float2int_rn(a.x  * FPSCALE));
        atomicAdd(row + 1,  __float2int_rn(a.y  * FPSCALE));
        atomicAdd(row + 2,  __float2int_rn(a.z  * FPSCALE));
        atomicAdd(row + 3,  __float2int_rn(a.w  * FPSCALE));
        atomicAdd(row + 4,  __float2int_rn(b.x  * FPSCALE));
        atomicAdd(row + 5,  __float2int_rn(b.y  * FPSCALE));
        atomicAdd(row + 6,  __float2int_rn(b.z  * FPSCALE));
        atomicAdd(row + 7,  __float2int_rn(b.w  * FPSCALE));
        atomicAdd(row + 8,  __float2int_rn(cc.x * FPSCALE));
        atomicAdd(row + 9,  __float2int_rn(cc.y * FPSCALE));
        atomicAdd(row + 10, __float2int_rn(cc.z * FPSCALE));
        atomicAdd(row + 11, __float2int_rn(cc.w * FPSCALE));
        atomicAdd(row + 12, __float2int_rn(dd.x * FPSCALE));
        atomicAdd(row + 13, __float2int_rn(dd.y * FPSCALE));
        atomicAdd(row + 14, __float2int_rn(dd.z * FPSCALE));
        atomicAdd(row + 15, __float2int_rn(dd.w * FPSCALE));
        atomicAdd(&s_cnt[c], 1u);
    }
    __syncthreads();
    for (int i = t; i < C * D; i += 256) {
        int c = i >> 4, d = i & 15;
        int s = s_sums[0 * REPSTRIDE + c * 17 + d]
              + s_sums[1 * REPSTRIDE + c * 17 + d]
              + s_sums[2 * REPSTRIDE + c * 17 + d]
              + s_sums[3 * REPSTRIDE + c * 17 + d];
        atomicAdd(&g_sums[i], (float)s * INV_FPSCALE);
    }
    if (t < C) atomicAdd(&g_cnt[t], s_cnt[t]);
}

__global__ __launch_bounds__(256) void k_hinge(const float4* __restrict__ f4,
                                               const int* __restrict__ labels, int N,
                                               const float* __restrict__ g_sums,
                                               const unsigned* __restrict__ g_cnt,
                                               float* __restrict__ g_var) {
    // register weighted sum: var_loss = sum_p h_p^2 / (C * count[label_p])
    __shared__ float s_means[C * 20];   // 20: float4-aligned rows, bank-spread
    __shared__ float s_w[C];
    __shared__ float s_red[256];
    int t = threadIdx.x;
    for (int i = t; i < C * D; i += 256) {
        int c = i >> 4, d = i & 15;
        s_means[c * 20 + d] = g_sums[i] / fmaxf((float)g_cnt[c], 1.0f);
    }
    if (t < C) s_w[t] = 1.0f / (fmaxf((float)g_cnt[t], 1.0f) * (float)C);
    __syncthreads();

    float acc = 0.0f;
    int gid = blockIdx.x * 256 + t;
    int stride = gridDim.x * 256;
    for (int p = gid; p < N; p += stride) {
        int c = labels[p] & (C - 1);
        const float* m = &s_means[c * 20];
        float4 m0 = *(const float4*)(m + 0);
        float4 m1 = *(const float4*)(m + 4);
        float4 m2 = *(const float4*)(m + 8);
        float4 m3 = *(const float4*)(m + 12);
        float4 a  = f4[4 * p + 0];
        float4 b  = f4[4 * p + 1];
        float4 cc = f4[4 * p + 2];
        float4 dd = f4[4 * p + 3];
        float ss = 0.0f, dx;
        dx = a.x - m0.x + EPSF; ss += dx * dx;
        dx = a.y - m0.y + EPSF; ss += dx * dx;
        dx = a.z - m0.z + EPSF; ss += dx * dx;
        dx = a.w - m0.w + EPSF; ss += dx * dx;
        dx = b.x - m1.x + EPSF; ss += dx * dx;
        dx = b.y - m1.y + EPSF; ss += dx * dx;
        dx = b.z - m1.z + EPSF; ss += dx * dx;
        dx = b.w - m1.w + EPSF; ss += dx * dx;
        dx = cc.x - m2.x + EPSF; ss += dx * dx;
        dx = cc.y - m2.y + EPSF; ss += dx * dx;
        dx = cc.z - m2.z + EPSF; ss += dx * dx;
        dx = cc.w - m2.w + EPSF; ss += dx * dx;
        dx = dd.x - m3.x + EPSF; ss += dx * dx;
        dx = dd.y - m3.y + EPSF; ss += dx * dx;
        dx = dd.z - m3.z + EPSF; ss += dx * dx;
        dx = dd.w - m3.w + EPSF; ss += dx * dx;
        float h = fmaxf(sqrtf(ss) - DVAR, 0.0f);
        acc += h * h * s_w[c];
    }
    s_red[t] = acc;
    __syncthreads();
    for (int s = 128; s > 0; s >>= 1) {
        if (t < s) s_red[t] += s_red[t + s];
        __syncthreads();
    }
    if (t == 0) atomicAdd(g_var, s_red[0]);
}

__global__ __launch_bounds__(256) void k_final(const float* __restrict__ g_sums,
                                               const unsigned* __restrict__ g_cnt,
                                               const float* __restrict__ g_var,
                                               float* __restrict__ out) {
    __shared__ float s_m[C * 17];
    __shared__ float red[256];
    int t = threadIdx.x;
    for (int i = t; i < C * D; i += 256) {
        int c = i >> 4, d = i & 15;
        s_m[c * 17 + d] = g_sums[i] / fmaxf((float)g_cnt[c], 1.0f);
    }
    __syncthreads();

    float var_loss = g_var[0];

    // dist_loss over ordered pairs i != j
    float ds = 0.0f;
    for (int p = t; p < C * C; p += 256) {
        int i = p >> 6, j = p & 63;
        if (i != j) {
            float ss = 0.0f;
            #pragma unroll
            for (int d = 0; d < D; d++) {
                float df = s_m[i * 17 + d] - s_m[j * 17 + d] + EPSF;
                ss += df * df;
            }
            float h = fmaxf(2.0f * DDIST - sqrtf(ss), 0.0f);
            ds += h * h;
        }
    }
    red[t] = ds;
    __syncthreads();
    for (int s = 128; s > 0; s >>= 1) {
        if (t < s) red[t] += red[t + s];
        __syncthreads();
    }
    float dist_loss = red[0] / (float)(C * (C - 1));
    __syncthreads();

    // reg_loss = mean_c ||m_c + EPS||
    float rg = 0.0f;
    if (t < C) {
        float ss = 0.0f;
        #pragma unroll
        for (int d = 0; d < D; d++) {
            float m = s_m[t * 17 + d] + EPSF;
            ss += m * m;
        }
        rg = sqrtf(ss);
    }
    red[t] = rg;
    __syncthreads();
    for (int s = 128; s > 0; s >>= 1) {
        if (t < s) red[t] += red[t + s];
        __syncthreads();
    }
    float reg_loss = red[0] / (float)C;

    if (t == 0) {
        out[0] = var_loss + dist_loss + 0.001f * reg_loss;
        out[1] = var_loss;
        out[2] = dist_loss;
        out[3] = reg_loss;
    }
}

extern "C" void kernel_launch(void* const* d_in, const int* in_sizes, int n_in,
                              void* d_out, int out_size, void* d_ws, size_t ws_size,
                              hipStream_t stream) {
    const float* features = (const float*)d_in[0];
    const int* labels = (const int*)d_in[1];
    int N = in_sizes[0] / D;

    float* ws = (float*)d_ws;
    float* g_sums = ws;                          // 1024 floats
    unsigned* g_cnt = (unsigned*)(ws + 1024);    // 64 uints
    float* g_var = ws + 1088;                    // 1 float
    float* out = (float*)d_out;

    hipLaunchKernelGGL(k_zero, dim3(5), dim3(256), 0, stream, ws, 1152);
    hipLaunchKernelGGL(k_sums, dim3(2048), dim3(256), 0, stream,
                       (const float4*)features, labels, N, g_sums, g_cnt);
    hipLaunchKernelGGL(k_hinge, dim3(2048), dim3(256), 0, stream,
                       (const float4*)features, labels, N, g_sums, g_cnt, g_var);
    hipLaunchKernelGGL(k_final, dim3(1), dim3(256), 0, stream, g_sums, g_cnt, g_var, out);
}

// Round 8
// 409.509 us; speedup vs baseline: 1.6108x; 1.0154x over previous
//
#include <hip/hip_runtime.h>
#include <math.h>

#define C 64
#define D 16
#define EPSF 1e-8f
#define DVAR 0.5f
#define DDIST 1.5f
#define FPSCALE 65536.0f
#define INV_FPSCALE (1.0f / 65536.0f)
#define VARSCALE 4294967296.0
#define INV_VARSCALE (1.0 / 4294967296.0)

// ws layout (32-bit words): [0,1024) g_sums (int, x2^16 fixed-point),
// [1024,1088) g_cnt (uint), [1088,1090) g_var (u64, x2^32 fixed-point; byte 4352, 8-aligned)
__global__ __launch_bounds__(256) void k_zero(int* ws, int n) {
    int i = blockIdx.x * 256 + threadIdx.x;
    if (i < n) ws[i] = 0;
}

__global__ __launch_bounds__(256) void k_sums(const float4* __restrict__ f4,
                                              const int* __restrict__ labels, int N,
                                              int* __restrict__ g_sums,
                                              unsigned* __restrict__ g_cnt) {
    // int fixed-point LDS histogram (native ds_add, round-6-proven).
    // REVERSE tile order: ends on the array head so k_hinge (forward) hits L3.
    __shared__ int s_sums[C * 17];
    __shared__ unsigned s_cnt[C];
    int t = threadIdx.x;
    for (int i = t; i < C * 17; i += 256) s_sums[i] = 0;
    if (t < C) s_cnt[t] = 0u;
    __syncthreads();

    int ntiles = (N + 255) >> 8;
    for (int it = blockIdx.x; it < ntiles; it += gridDim.x) {
        int tile = ntiles - 1 - it;
        int p = (tile << 8) + t;
        if (p >= N) continue;
        int c = labels[p] & (C - 1);
        float4 a  = f4[4 * p + 0];
        float4 b  = f4[4 * p + 1];
        float4 cc = f4[4 * p + 2];
        float4 dd = f4[4 * p + 3];
        int* row = &s_sums[c * 17];
        atomicAdd(row + 0,  __float2int_rn(a.x  * FPSCALE));
        atomicAdd(row + 1,  __float2int_rn(a.y  * FPSCALE));
        atomicAdd(row + 2,  __float2int_rn(a.z  * FPSCALE));
        atomicAdd(row + 3,  __float2int_rn(a.w  * FPSCALE));
        atomicAdd(row + 4,  __float2int_rn(b.x  * FPSCALE));
        atomicAdd(row + 5,  __float2int_rn(b.y  * FPSCALE));
        atomicAdd(row + 6,  __float2int_rn(b.z  * FPSCALE));
        atomicAdd(row + 7,  __float2int_rn(b.w  * FPSCALE));
        atomicAdd(row + 8,  __float2int_rn(cc.x * FPSCALE));
        atomicAdd(row + 9,  __float2int_rn(cc.y * FPSCALE));
        atomicAdd(row + 10, __float2int_rn(cc.z * FPSCALE));
        atomicAdd(row + 11, __float2int_rn(cc.w * FPSCALE));
        atomicAdd(row + 12, __float2int_rn(dd.x * FPSCALE));
        atomicAdd(row + 13, __float2int_rn(dd.y * FPSCALE));
        atomicAdd(row + 14, __float2int_rn(dd.z * FPSCALE));
        atomicAdd(row + 15, __float2int_rn(dd.w * FPSCALE));
        atomicAdd(&s_cnt[c], 1u);
    }
    __syncthreads();
    // flush with NATIVE int global atomics (fp atomicAdd w/o -munsafe-fp-atomics = CAS loop)
    for (int i = t; i < C * D; i += 256) {
        int c = i >> 4, d = i & 15;
        atomicAdd(&g_sums[i], s_sums[c * 17 + d]);
    }
    if (t < C) atomicAdd(&g_cnt[t], s_cnt[t]);
}

__global__ __launch_bounds__(256) void k_hinge(const float4* __restrict__ f4,
                                               const int* __restrict__ labels, int N,
                                               const int* __restrict__ g_sums,
                                               const unsigned* __restrict__ g_cnt,
                                               unsigned long long* __restrict__ g_var) {
    // register weighted sum: var_loss = sum_p h_p^2 / (C * count[label_p]);
    // forward order to consume the L3-resident head left by k_sums.
    __shared__ float s_means[C * 20];
    __shared__ float s_w[C];
    __shared__ float s_red[256];
    int t = threadIdx.x;
    for (int i = t; i < C * D; i += 256) {
        int c = i >> 4, d = i & 15;
        s_means[c * 20 + d] = (float)g_sums[i] * INV_FPSCALE / fmaxf((float)g_cnt[c], 1.0f);
    }
    if (t < C) s_w[t] = 1.0f / (fmaxf((float)g_cnt[t], 1.0f) * (float)C);
    __syncthreads();

    float acc = 0.0f;
    int gid = blockIdx.x * 256 + t;
    int stride = gridDim.x * 256;
    for (int p = gid; p < N; p += stride) {
        int c = labels[p] & (C - 1);
        const float* m = &s_means[c * 20];
        float4 m0 = *(const float4*)(m + 0);
        float4 m1 = *(const float4*)(m + 4);
        float4 m2 = *(const float4*)(m + 8);
        float4 m3 = *(const float4*)(m + 12);
        float4 a  = f4[4 * p + 0];
        float4 b  = f4[4 * p + 1];
        float4 cc = f4[4 * p + 2];
        float4 dd = f4[4 * p + 3];
        float ss = 0.0f, dx;
        dx = a.x - m0.x + EPSF; ss += dx * dx;
        dx = a.y - m0.y + EPSF; ss += dx * dx;
        dx = a.z - m0.z + EPSF; ss += dx * dx;
        dx = a.w - m0.w + EPSF; ss += dx * dx;
        dx = b.x - m1.x + EPSF; ss += dx * dx;
        dx = b.y - m1.y + EPSF; ss += dx * dx;
        dx = b.z - m1.z + EPSF; ss += dx * dx;
        dx = b.w - m1.w + EPSF; ss += dx * dx;
        dx = cc.x - m2.x + EPSF; ss += dx * dx;
        dx = cc.y - m2.y + EPSF; ss += dx * dx;
        dx = cc.z - m2.z + EPSF; ss += dx * dx;
        dx = cc.w - m2.w + EPSF; ss += dx * dx;
        dx = dd.x - m3.x + EPSF; ss += dx * dx;
        dx = dd.y - m3.y + EPSF; ss += dx * dx;
        dx = dd.z - m3.z + EPSF; ss += dx * dx;
        dx = dd.w - m3.w + EPSF; ss += dx * dx;
        float h = fmaxf(sqrtf(ss) - DVAR, 0.0f);
        acc += h * h * s_w[c];
    }
    s_red[t] = acc;
    __syncthreads();
    for (int s = 128; s > 0; s >>= 1) {
        if (t < s) s_red[t] += s_red[t + s];
        __syncthreads();
    }
    // one NATIVE u64 atomic per block (partials are non-negative)
    if (t == 0) {
        unsigned long long q = (unsigned long long)((double)s_red[0] * VARSCALE + 0.5);
        atomicAdd(g_var, q);
    }
}

__global__ __launch_bounds__(256) void k_final(const int* __restrict__ g_sums,
                                               const unsigned* __restrict__ g_cnt,
                                               const unsigned long long* __restrict__ g_var,
                                               float* __restrict__ out) {
    __shared__ float s_m[C * 17];
    __shared__ float red[256];
    int t = threadIdx.x;
    for (int i = t; i < C * D; i += 256) {
        int c = i >> 4, d = i & 15;
        s_m[c * 17 + d] = (float)g_sums[i] * INV_FPSCALE / fmaxf((float)g_cnt[c], 1.0f);
    }
    __syncthreads();

    float var_loss = (float)((double)g_var[0] * INV_VARSCALE);

    // dist_loss over ordered pairs i != j
    float ds = 0.0f;
    for (int p = t; p < C * C; p += 256) {
        int i = p >> 6, j = p & 63;
        if (i != j) {
            float ss = 0.0f;
            #pragma unroll
            for (int d = 0; d < D; d++) {
                float df = s_m[i * 17 + d] - s_m[j * 17 + d] + EPSF;
                ss += df * df;
            }
            float h = fmaxf(2.0f * DDIST - sqrtf(ss), 0.0f);
            ds += h * h;
        }
    }
    red[t] = ds;
    __syncthreads();
    for (int s = 128; s > 0; s >>= 1) {
        if (t < s) red[t] += red[t + s];
        __syncthreads();
    }
    float dist_loss = red[0] / (float)(C * (C - 1));
    __syncthreads();

    // reg_loss = mean_c ||m_c + EPS||
    float rg = 0.0f;
    if (t < C) {
        float ss = 0.0f;
        #pragma unroll
        for (int d = 0; d < D; d++) {
            float m = s_m[t * 17 + d] + EPSF;
            ss += m * m;
        }
        rg = sqrtf(ss);
    }
    red[t] = rg;
    __syncthreads();
    for (int s = 128; s > 0; s >>= 1) {
        if (t < s) red[t] += red[t + s];
        __syncthreads();
    }
    float reg_loss = red[0] / (float)C;

    if (t == 0) {
        out[0] = var_loss + dist_loss + 0.001f * reg_loss;
        out[1] = var_loss;
        out[2] = dist_loss;
        out[3] = reg_loss;
    }
}

extern "C" void kernel_launch(void* const* d_in, const int* in_sizes, int n_in,
                              void* d_out, int out_size, void* d_ws, size_t ws_size,
                              hipStream_t stream) {
    const float* features = (const float*)d_in[0];
    const int* labels = (const int*)d_in[1];
    int N = in_sizes[0] / D;

    int* ws = (int*)d_ws;
    int* g_sums = ws;                                          // 1024 ints (x2^16)
    unsigned* g_cnt = (unsigned*)(ws + 1024);                  // 64 uints
    unsigned long long* g_var = (unsigned long long*)(ws + 1088); // u64 (x2^32), 8-aligned
    float* out = (float*)d_out;

    hipLaunchKernelGGL(k_zero, dim3(5), dim3(256), 0, stream, ws, 1090);
    hipLaunchKernelGGL(k_sums, dim3(2048), dim3(256), 0, stream,
                       (const float4*)features, labels, N, g_sums, g_cnt);
    hipLaunchKernelGGL(k_hinge, dim3(2048), dim3(256), 0, stream,
                       (const float4*)features, labels, N, g_sums, g_cnt, g_var);
    hipLaunchKernelGGL(k_final, dim3(1), dim3(256), 0, stream, g_sums, g_cnt, g_var, out);
}